// Round 5
// baseline (41.709 us; speedup 1.0000x reference)
//
#include <hip/hip_runtime.h>
#include <math.h>

#define N 8192
#define D 64
#define KK 5                          // K-steps of 16 (K=80: 64 data + 4 norm + 12 zero)
#define JSPLIT 8
#define ITW (256 / JSPLIT / 4)        // 8 j-tiles per wave
#define LOG2E 1.4426950408889634f
#define C2 2.0813689810056077f        // (log2 e)^2
#define SA (-2.0f * LOG2E)
#define SB LOG2E
#define LN2 0.6931471805599453f
#define BIG 3.0e38f
#define EXPBIAS 0.9608944f            // 1 / E[(1+g) 2^-g], g~U[0,1)
#define EXPMAGIC 1065353216.0f        // 127 << 23
#define EXPSCALE -8388608.0f          // -2^23

typedef short bf16x8 __attribute__((ext_vector_type(8)));
typedef float f32x16 __attribute__((ext_vector_type(16)));

static __device__ __forceinline__ unsigned short f2bf(float f) {
    unsigned int u = __float_as_uint(f);
    return (unsigned short)((u + 0x7fffu + ((u >> 16) & 1u)) >> 16);
}

// Fragment layout (validated r2-r4): 16B slot s = (tile*KK + kk)*64 + lane;
// lane l holds row (l&31), k = kk*16 + 8*(l>>5) + 0..7.
// A (xba): k<64 -> -2*log2e*x ; k=64..67 -> [nhi, nlo, 1, 1] ; rest 0
// B (xbb): k<64 ->    log2e*x ; k=64..67 -> [1, 1, nhi, nlo] ; rest 0
// => acc[j,i] = |log2e * (x_i - x_j)|^2
__global__ __launch_bounds__(256) void prep_kernel(const float* __restrict__ x,
                                                   unsigned short* __restrict__ xba,
                                                   unsigned short* __restrict__ xbb) {
    const int u = blockIdx.x * 256 + threadIdx.x;
    const int r = u >> 3, oct = u & 7;
    const float4 v0 = *(const float4*)(x + r * D + oct * 8);
    const float4 v1 = *(const float4*)(x + r * D + oct * 8 + 4);
    float s = v0.x * v0.x + v0.y * v0.y + v0.z * v0.z + v0.w * v0.w
            + v1.x * v1.x + v1.y * v1.y + v1.z * v1.z + v1.w * v1.w;
    s += __shfl_xor(s, 1); s += __shfl_xor(s, 2); s += __shfl_xor(s, 4);

    const int slot = ((r >> 5) * KK + (oct >> 1)) * 64 + (r & 31) + 32 * (oct & 1);
    uint4 wa, wb;
    wa.x = (unsigned)f2bf(SA * v0.x) | ((unsigned)f2bf(SA * v0.y) << 16);
    wa.y = (unsigned)f2bf(SA * v0.z) | ((unsigned)f2bf(SA * v0.w) << 16);
    wa.z = (unsigned)f2bf(SA * v1.x) | ((unsigned)f2bf(SA * v1.y) << 16);
    wa.w = (unsigned)f2bf(SA * v1.z) | ((unsigned)f2bf(SA * v1.w) << 16);
    wb.x = (unsigned)f2bf(SB * v0.x) | ((unsigned)f2bf(SB * v0.y) << 16);
    wb.y = (unsigned)f2bf(SB * v0.z) | ((unsigned)f2bf(SB * v0.w) << 16);
    wb.z = (unsigned)f2bf(SB * v1.x) | ((unsigned)f2bf(SB * v1.y) << 16);
    wb.w = (unsigned)f2bf(SB * v1.z) | ((unsigned)f2bf(SB * v1.w) << 16);
    *(uint4*)(xba + (size_t)slot * 8) = wa;
    *(uint4*)(xbb + (size_t)slot * 8) = wb;

    const float np = C2 * s;
    const unsigned short nhi = f2bf(np);
    const unsigned short nlo = f2bf(np - __uint_as_float((unsigned)nhi << 16));
    const int nbase = ((r >> 5) * KK + 4) * 64 + (r & 31);
    const unsigned ONE2 = 0x3f803f80u;
    if (oct == 0) {
        uint4 w; w.x = (unsigned)nhi | ((unsigned)nlo << 16); w.y = ONE2; w.z = 0; w.w = 0;
        *(uint4*)(xba + (size_t)nbase * 8) = w;
    } else if (oct == 1) {
        uint4 w; w.x = 0; w.y = 0; w.z = 0; w.w = 0;
        *(uint4*)(xba + (size_t)(nbase + 32) * 8) = w;
    } else if (oct == 2) {
        uint4 w; w.x = ONE2; w.y = (unsigned)nhi | ((unsigned)nlo << 16); w.z = 0; w.w = 0;
        *(uint4*)(xbb + (size_t)nbase * 8) = w;
    } else if (oct == 3) {
        uint4 w; w.x = 0; w.y = 0; w.z = 0; w.w = 0;
        *(uint4*)(xbb + (size_t)(nbase + 32) * 8) = w;
    }
}

template<bool DIAG>
static __device__ __forceinline__ void epi(const f32x16& acc, int hi, int il,
                                           float& s1a, float& s2a, float& sea,
                                           float& s1b, float& s2b, float& seb) {
#pragma unroll
    for (int q = 0; q < 16; ++q) {
        float sq = acc[q];
        if (DIAG) {
            sq = fmaxf(sq, 0.0f);
            const bool self = ((q & 3) + 8 * (q >> 2) + 4 * hi) == il;
            sq = self ? BIG : sq;      // self: e becomes -0.0 via cvt-saturate, harmless
        }
        const float dd = __builtin_amdgcn_sqrtf(sq);           // log2e * dist
        const float ef = fmaf(dd, EXPSCALE, EXPMAGIC);         // fast 2^(-dd)
        const float e  = __int_as_float((int)ef);
        if (q & 1) { seb += e; s2b = __builtin_amdgcn_fmed3f(s1b, s2b, sq); s1b = fminf(s1b, sq); }
        else       { sea += e; s2a = __builtin_amdgcn_fmed3f(s1a, s2a, sq); s1a = fminf(s1a, sq); }
    }
}

__global__ __launch_bounds__(256, 5) void knn_mfma_kernel(
        const unsigned short* __restrict__ xba,
        const unsigned short* __restrict__ xbb,
        float* __restrict__ partials) {
    __shared__ float s_red[4 * 96];

    const int t = threadIdx.x;
    const int lane = t & 63;
    const int w = __builtin_amdgcn_readfirstlane(t >> 6);
    const int itile = blockIdx.x >> 3;
    const int js = blockIdx.x & (JSPLIT - 1);
    const int il = lane & 31, hi = lane >> 5;

    bf16x8 xi[KK];
#pragma unroll
    for (int kk = 0; kk < KK; ++kk)
        xi[kk] = *(const bf16x8*)(xbb + ((size_t)(itile * KK + kk) * 64 + lane) * 8);

    const int jt0 = (js * 4 + w) * ITW;
    float s1a = BIG, s2a = BIG, sea = 0.0f;
    float s1b = BIG, s2b = BIG, seb = 0.0f;
    const f32x16 zacc = {};

#pragma unroll 2
    for (int it = 0; it < ITW; ++it) {
        const int jt = jt0 + it;
        const unsigned short* base = xba + ((size_t)jt * KK * 64 + lane) * 8;
        bf16x8 aj[KK];
#pragma unroll
        for (int kk = 0; kk < KK; ++kk) aj[kk] = *(const bf16x8*)(base + kk * 64 * 8);
        f32x16 acc = __builtin_amdgcn_mfma_f32_32x32x16_bf16(aj[0], xi[0], zacc, 0, 0, 0);
#pragma unroll
        for (int kk = 1; kk < KK; ++kk)
            acc = __builtin_amdgcn_mfma_f32_32x32x16_bf16(aj[kk], xi[kk], acc, 0, 0, 0);
        if (jt == itile) epi<true >(acc, hi, il, s1a, s2a, sea, s1b, s2b, seb);
        else             epi<false>(acc, hi, il, s1a, s2a, sea, s1b, s2b, seb);
    }

    // merge even/odd sets (squared domain)
    float s1 = fminf(s1a, s1b);
    float s2 = fminf(fmaxf(s1a, s1b), fminf(s2a, s2b));
    float se = sea + seb;

    // lane <-> lane^32: same i, disjoint j rows
    {
        const float o1 = __shfl_xor(s1, 32);
        const float o2 = __shfl_xor(s2, 32);
        const float os = __shfl_xor(se, 32);
        const float n1 = fminf(s1, o1);
        const float n2 = fminf(fmaxf(s1, o1), fminf(s2, o2));
        s1 = n1; s2 = n2; se += os;
    }
    if (lane < 32) {
        s_red[w * 96 + lane]      = s1;
        s_red[w * 96 + 32 + lane] = s2;
        s_red[w * 96 + 64 + lane] = se;
    }
    __syncthreads();
    if (t < 32) {
        float a1 = s_red[t], a2 = s_red[32 + t], as = s_red[64 + t];
#pragma unroll
        for (int g = 1; g < 4; ++g) {
            const float b1 = s_red[g * 96 + t], b2 = s_red[g * 96 + 32 + t];
            const float m1 = fminf(a1, b1);
            const float m2 = fminf(fmaxf(a1, b1), fminf(a2, b2));
            a1 = m1; a2 = m2; as += s_red[g * 96 + 64 + t];
        }
        float* P = partials + (size_t)blockIdx.x * 96;
        P[t] = a1; P[32 + t] = a2; P[64 + t] = as;
    }
}

__global__ __launch_bounds__(1024) void merge_kernel(const float* __restrict__ partials,
                                                     float* __restrict__ out) {
    __shared__ float s_s[16];
    const int t = threadIdx.x;
    float sum = 0.0f;
#pragma unroll
    for (int it = 0; it < 8; ++it) {
        const int p = t + it * 1024;
        const int itile = p >> 5, il = p & 31;
        const float* P = partials + (size_t)itile * JSPLIT * 96;
        float a1 = P[il], a2 = P[32 + il], as = P[64 + il];
#pragma unroll
        for (int jsp = 1; jsp < JSPLIT; ++jsp) {
            const float* Q = P + jsp * 96;
            const float b1 = Q[il], b2 = Q[32 + il];
            const float m1 = fminf(a1, b1);
            const float m2 = fminf(fmaxf(a1, b1), fminf(a2, b2));
            a1 = m1; a2 = m2; as += Q[64 + il];
        }
        // a1,a2 are squared scaled dists; se needs bit-trick bias correction
        sum += 0.5f * LN2 * (sqrtf(a1) + sqrtf(a2)) + logf(EXPBIAS * as);
    }
#pragma unroll
    for (int off = 32; off >= 1; off >>= 1) sum += __shfl_xor(sum, off);
    if ((t & 63) == 0) s_s[t >> 6] = sum;
    __syncthreads();
    if (t == 0) {
        float tot = 0.0f;
#pragma unroll
        for (int g = 0; g < 16; ++g) tot += s_s[g];
        out[0] = tot * (1.0f / (float)N);
    }
}

extern "C" void kernel_launch(void* const* d_in, const int* in_sizes, int n_in,
                              void* d_out, int out_size, void* d_ws, size_t ws_size,
                              hipStream_t stream) {
    const float* x = (const float*)d_in[0];
    float* out = (float*)d_out;
    char* ws = (char*)d_ws;
    unsigned short* xba = (unsigned short*)ws;
    unsigned short* xbb = xba + (size_t)(N / 32) * KK * 64 * 8;
    float* partials = (float*)(xbb + (size_t)(N / 32) * KK * 64 * 8);

    prep_kernel<<<(N * 8) / 256, 256, 0, stream>>>(x, xba, xbb);
    knn_mfma_kernel<<<(N / 32) * JSPLIT, 256, 0, stream>>>(xba, xbb, partials);
    merge_kernel<<<1, 1024, 0, stream>>>(partials, out);
}

// Round 6
// 38.538 us; speedup vs baseline: 1.0823x; 1.0823x over previous
//
#include <hip/hip_runtime.h>
#include <math.h>

#define N 8192
#define D 64
#define KK 4                          // K-steps of 16 (K=64)
#define WAVES 8
#define PANEL 256                     // j-rows staged per iteration (8 jtiles)
#define NPANEL 16                     // panels per block (j-half = 4096 rows)
#define LOG2E 1.4426950408889634f
#define C2 2.0813689810056077f        // (log2 e)^2
#define SA (-2.0f * LOG2E)
#define SB LOG2E
#define LN2 0.6931471805599453f
#define BIG 3.0e38f
#define EXPBIAS 0.9608944f            // 1 / E[(1+g) 2^-g], g~U[0,1)
#define EXPMAGIC 1065353216.0f        // 127 << 23
#define EXPSCALE -8388608.0f          // -2^23

typedef short bf16x8 __attribute__((ext_vector_type(8)));
typedef float f32x16 __attribute__((ext_vector_type(16)));

static __device__ __forceinline__ unsigned short f2bf(float f) {
    unsigned int u = __float_as_uint(f);
    return (unsigned short)((u + 0x7fffu + ((u >> 16) & 1u)) >> 16);
}

// Fragment layout (validated r2-r5): 16B slot s = (tile*KK + kk)*64 + lane;
// lane l holds row (l&31), k = kk*16 + 8*(l>>5) + 0..7.
// xba = -2*log2e*x (A operand), xbb = log2e*x (B operand), cn = (log2e)^2*|x|^2
// => sq' = cni + cnj + acc = |log2e*(x_i - x_j)|^2
__global__ __launch_bounds__(256) void prep_kernel(const float* __restrict__ x,
                                                   unsigned short* __restrict__ xba,
                                                   unsigned short* __restrict__ xbb,
                                                   float* __restrict__ cn) {
    const int u = blockIdx.x * 256 + threadIdx.x;
    const int r = u >> 3, oct = u & 7;
    const float4 v0 = *(const float4*)(x + r * D + oct * 8);
    const float4 v1 = *(const float4*)(x + r * D + oct * 8 + 4);
    float s = v0.x * v0.x + v0.y * v0.y + v0.z * v0.z + v0.w * v0.w
            + v1.x * v1.x + v1.y * v1.y + v1.z * v1.z + v1.w * v1.w;
    s += __shfl_xor(s, 1); s += __shfl_xor(s, 2); s += __shfl_xor(s, 4);
    if (oct == 0) cn[r] = C2 * s;
    uint4 wa, wb;
    wa.x = (unsigned)f2bf(SA * v0.x) | ((unsigned)f2bf(SA * v0.y) << 16);
    wa.y = (unsigned)f2bf(SA * v0.z) | ((unsigned)f2bf(SA * v0.w) << 16);
    wa.z = (unsigned)f2bf(SA * v1.x) | ((unsigned)f2bf(SA * v1.y) << 16);
    wa.w = (unsigned)f2bf(SA * v1.z) | ((unsigned)f2bf(SA * v1.w) << 16);
    wb.x = (unsigned)f2bf(SB * v0.x) | ((unsigned)f2bf(SB * v0.y) << 16);
    wb.y = (unsigned)f2bf(SB * v0.z) | ((unsigned)f2bf(SB * v0.w) << 16);
    wb.z = (unsigned)f2bf(SB * v1.x) | ((unsigned)f2bf(SB * v1.y) << 16);
    wb.w = (unsigned)f2bf(SB * v1.z) | ((unsigned)f2bf(SB * v1.w) << 16);
    const int slot = ((r >> 5) * KK + (oct >> 1)) * 64 + (r & 31) + 32 * (oct & 1);
    *(uint4*)(xba + (size_t)slot * 8) = wa;
    *(uint4*)(xbb + (size_t)slot * 8) = wb;
}

template<bool DIAG>
static __device__ __forceinline__ void epi(const f32x16& acc, const float* s_njw,
                                           float cni, int hi, int il,
                                           float& s1a, float& s2a, float& sea,
                                           float& s1b, float& s2b, float& seb) {
#pragma unroll
    for (int g = 0; g < 4; ++g) {
        const float4 nj4 = *(const float4*)(s_njw + 8 * g + 4 * hi);
#pragma unroll
        for (int b = 0; b < 4; ++b) {
            const int q = g * 4 + b;
            float sq = (cni + ((const float*)&nj4)[b]) + acc[q];
            if (DIAG) {
                sq = fmaxf(sq, 0.0f);
                const bool self = (8 * g + 4 * hi + b) == il;
                sq = self ? BIG : sq;   // bit-exp of sqrt(BIG) saturates to -0.0
            }
            const float dd = __builtin_amdgcn_sqrtf(sq);       // log2e * dist
            const float ef = fmaf(dd, EXPSCALE, EXPMAGIC);     // fast 2^(-dd)
            const float e  = __int_as_float((int)ef);
            if (q & 1) { seb += e; s2b = __builtin_amdgcn_fmed3f(s1b, s2b, sq); s1b = fminf(s1b, sq); }
            else       { sea += e; s2a = __builtin_amdgcn_fmed3f(s1a, s2a, sq); s1a = fminf(s1a, sq); }
        }
    }
}

__global__ __launch_bounds__(512) void knn_mfma_kernel(
        const unsigned short* __restrict__ xba,
        const unsigned short* __restrict__ xbb,
        const float* __restrict__ cn,
        float* __restrict__ partials) {
    __shared__ uint4 s_xj[2048];          // 32 KB: 8 jtiles x 4 kk x 64 lanes
    __shared__ float s_nj[PANEL];         // 1 KB
    __shared__ float s_red[WAVES * 96];   // 3 KB

    const int t = threadIdx.x;
    const int lane = t & 63;
    const int w = __builtin_amdgcn_readfirstlane(t >> 6);
    const int itile = blockIdx.x >> 1;
    const int h = blockIdx.x & 1;
    const int il = lane & 31, hi = lane >> 5;
    const float cni = cn[itile * 32 + il];

    bf16x8 xi[KK];
#pragma unroll
    for (int kk = 0; kk < KK; ++kk)
        xi[kk] = *(const bf16x8*)(xbb + ((size_t)(itile * KK + kk) * 64 + lane) * 8);

    float s1a = BIG, s2a = BIG, sea = 0.0f;
    float s1b = BIG, s2b = BIG, seb = 0.0f;
    const f32x16 zacc = {};

    for (int it = 0; it < NPANEL; ++it) {
        const int jtile0 = h * 128 + it * 8;
        __syncthreads();
        // stage 8 jtiles (32 KB) of fragment-order bf16; linear dest, wave-uniform base
#pragma unroll
        for (int p = 0; p < 4; ++p) {
            const int c = p * 8 + w;   // 1 KB chunk = 64 slots
            const unsigned short* g = xba + ((size_t)jtile0 * 256 + c * 64 + lane) * 8;
            __builtin_amdgcn_global_load_lds(
                (const __attribute__((address_space(1))) unsigned int*)g,
                (__attribute__((address_space(3))) unsigned int*)(s_xj + c * 64),
                16, 0, 0);
        }
        if (t < PANEL) s_nj[t] = cn[jtile0 * 32 + t];
        __syncthreads();   // compiler drains vmcnt/lgkmcnt before barrier

        const int jt = jtile0 + w;    // this wave's jtile
        const unsigned short* sb = (const unsigned short*)s_xj;
        bf16x8 aj[KK];
#pragma unroll
        for (int kk = 0; kk < KK; ++kk)
            aj[kk] = *(const bf16x8*)(sb + ((w * KK + kk) * 64 + lane) * 8);
        f32x16 acc = __builtin_amdgcn_mfma_f32_32x32x16_bf16(aj[0], xi[0], zacc, 0, 0, 0);
#pragma unroll
        for (int kk = 1; kk < KK; ++kk)
            acc = __builtin_amdgcn_mfma_f32_32x32x16_bf16(aj[kk], xi[kk], acc, 0, 0, 0);

        const float* s_njw = s_nj + w * 32;
        if (jt == itile) epi<true >(acc, s_njw, cni, hi, il, s1a, s2a, sea, s1b, s2b, seb);
        else             epi<false>(acc, s_njw, cni, hi, il, s1a, s2a, sea, s1b, s2b, seb);
    }

    // merge even/odd sets (squared domain)
    float s1 = fminf(s1a, s1b);
    float s2 = fminf(fmaxf(s1a, s1b), fminf(s2a, s2b));
    float se = sea + seb;

    // lane <-> lane^32: same i, disjoint j rows
    {
        const float o1 = __shfl_xor(s1, 32);
        const float o2 = __shfl_xor(s2, 32);
        const float os = __shfl_xor(se, 32);
        const float n1 = fminf(s1, o1);
        const float n2 = fminf(fmaxf(s1, o1), fminf(s2, o2));
        s1 = n1; s2 = n2; se += os;
    }
    if (lane < 32) {
        s_red[w * 96 + lane]      = s1;
        s_red[w * 96 + 32 + lane] = s2;
        s_red[w * 96 + 64 + lane] = se;
    }
    __syncthreads();
    if (t < 32) {
        float a1 = s_red[t], a2 = s_red[32 + t], as = s_red[64 + t];
#pragma unroll
        for (int g = 1; g < WAVES; ++g) {
            const float b1 = s_red[g * 96 + t], b2 = s_red[g * 96 + 32 + t];
            const float m1 = fminf(a1, b1);
            const float m2 = fminf(fmaxf(a1, b1), fminf(a2, b2));
            a1 = m1; a2 = m2; as += s_red[g * 96 + 64 + t];
        }
        float* P = partials + (size_t)blockIdx.x * 96;
        P[t] = a1; P[32 + t] = a2; P[64 + t] = as;
    }
}

__global__ __launch_bounds__(1024) void merge_kernel(const float* __restrict__ partials,
                                                     float* __restrict__ out) {
    __shared__ float s_s[16];
    const int t = threadIdx.x;
    float sum = 0.0f;
#pragma unroll
    for (int it = 0; it < 8; ++it) {
        const int p = t + it * 1024;
        const int itile = p >> 5, il = p & 31;
        const float* P = partials + (size_t)itile * 2 * 96;
        const float* Q = P + 96;
        const float a1 = P[il], a2 = P[32 + il];
        const float b1 = Q[il], b2 = Q[32 + il];
        const float m1 = fminf(a1, b1);
        const float m2 = fminf(fmaxf(a1, b1), fminf(a2, b2));
        const float as = P[64 + il] + Q[64 + il];
        sum += 0.5f * LN2 * (sqrtf(m1) + sqrtf(m2)) + logf(EXPBIAS * as);
    }
#pragma unroll
    for (int off = 32; off >= 1; off >>= 1) sum += __shfl_xor(sum, off);
    if ((t & 63) == 0) s_s[t >> 6] = sum;
    __syncthreads();
    if (t == 0) {
        float tot = 0.0f;
#pragma unroll
        for (int g = 0; g < 16; ++g) tot += s_s[g];
        out[0] = tot * (1.0f / (float)N);
    }
}

extern "C" void kernel_launch(void* const* d_in, const int* in_sizes, int n_in,
                              void* d_out, int out_size, void* d_ws, size_t ws_size,
                              hipStream_t stream) {
    const float* x = (const float*)d_in[0];
    float* out = (float*)d_out;
    char* ws = (char*)d_ws;
    unsigned short* xba = (unsigned short*)ws;                       // 1 MB
    unsigned short* xbb = xba + (size_t)(N / 32) * KK * 64 * 8;      // 1 MB
    float* cn = (float*)(xbb + (size_t)(N / 32) * KK * 64 * 8);      // 32 KB
    float* partials = cn + N;                                        // 512*96 f32

    prep_kernel<<<(N * 8) / 256, 256, 0, stream>>>(x, xba, xbb, cn);
    knn_mfma_kernel<<<(N / 32) * 2, 512, 0, stream>>>(xba, xbb, cn, partials);
    merge_kernel<<<1, 1024, 0, stream>>>(partials, out);
}